// Round 9
// baseline (369.131 us; speedup 1.0000x reference)
//
#include <hip/hip_runtime.h>
#include <hip/hip_bf16.h>

typedef unsigned short u16;
typedef __bf16 bf16x8 __attribute__((ext_vector_type(8)));
typedef u16 u16x8 __attribute__((ext_vector_type(8)));
typedef float f32x4 __attribute__((ext_vector_type(4)));

__device__ __forceinline__ float bf2f(u16 u) {
    return __uint_as_float(((unsigned)u) << 16);
}
__device__ __forceinline__ u16 f2bf(float f) {
    unsigned u = __float_as_uint(f);
    unsigned r = (u + 0x7fffu + ((u >> 16) & 1u)) >> 16;
    return (u16)r;
}

// async global->LDS, 16B per lane. dst is wave-uniform base; HW adds lane*16.
__device__ __forceinline__ void gl_lds16(const u16* g, u16* l) {
    __builtin_amdgcn_global_load_lds(
        (const __attribute__((address_space(1))) void*)g,
        (__attribute__((address_space(3))) void*)l, 16, 0, 0);
}

// ---------------- fused prep: x f32->bf16 convert + 3 weight transposes ----------------
// blocks [0,10280): convert; [10280,10472): Wv; [10472,10664): Wa; [10664,10728): Wo
__global__ __launch_bounds__(256) void prep(const float* __restrict__ x,
                                            const float* __restrict__ Wv,
                                            const float* __restrict__ Wa,
                                            const float* __restrict__ Wo,
                                            u16* __restrict__ xb,
                                            u16* __restrict__ WvT,
                                            u16* __restrict__ WaT,
                                            u16* __restrict__ WoT) {
    __shared__ float tile[64][65];
    int blk = blockIdx.x;
    if (blk < 10280) {
        int i = (blk * 256 + threadIdx.x) * 8;
        float4 a = *(const float4*)&x[i];
        float4 b = *(const float4*)&x[i + 4];
        u16x8 o;
        o[0] = f2bf(a.x); o[1] = f2bf(a.y); o[2] = f2bf(a.z); o[3] = f2bf(a.w);
        o[4] = f2bf(b.x); o[5] = f2bf(b.y); o[6] = f2bf(b.z); o[7] = f2bf(b.w);
        *(u16x8*)&xb[i] = o;
        return;
    }
    blk -= 10280;
    const float* W; u16* WT; int N;
    if (blk < 192)      { W = Wv; WT = WvT; N = 1536; }
    else if (blk < 384) { W = Wa; WT = WaT; N = 1536; blk -= 192; }
    else                { W = Wo; WT = WoT; N = 512;  blk -= 384; }
    const int K = 512;
    const int nt = N >> 6;
    const int k0 = (blk / nt) << 6;
    const int n0 = (blk % nt) << 6;
    for (int i = threadIdx.x; i < 4096; i += 256) {
        int r = i >> 6, c = i & 63;
        tile[r][c] = W[(size_t)(k0 + r) * N + n0 + c];
    }
    __syncthreads();
    for (int i = threadIdx.x; i < 4096; i += 256) {
        int r = i >> 6, c = i & 63;
        WT[(size_t)(n0 + r) * K + k0 + c] = f2bf(tile[c][r]);
    }
}

// ---------------- generic MFMA GEMM (used for A-projection and out-proj) ----------
// MODE 0: row r -> r (clamp).  MODE 2: r -> r*257 (clamp). OUTF: float out (+bias).
template <int MODE, int OUTF>
__global__ __launch_bounds__(256) void gemm_k(const u16* __restrict__ A,
                                              const u16* __restrict__ Bt,
                                              void* __restrict__ Cv,
                                              const float* __restrict__ bias,
                                              int M, int N, int K) {
    __shared__ u16 As[128][64];
    __shared__ u16 Bs[128][64];
    const int t = threadIdx.x;
    const int bn0 = blockIdx.x * 128;
    const int bm0 = blockIdx.y * 128;
    const int wave = t >> 6, lane = t & 63;
    const int wm = (wave >> 1) * 64, wn = (wave & 1) * 64;
    const int lr = lane & 15, lh = lane >> 4;
    const int srow = wave * 8 + (lane >> 3);
    const int scol = (lane & 7) * 8;

    f32x4 acc[4][4] = {};

    for (int kt = 0; kt < K; kt += 64) {
        __syncthreads();
#pragma unroll
        for (int i = 0; i < 4; i++) {
            int row = i * 32 + srow;
            int r = bm0 + row;
            long g;
            if (MODE == 0) g = (r < M) ? (long)r : 0l;
            else           g = (r < M) ? (long)r * 257 : 0l;
            gl_lds16(&A[g * K + kt + scol], &As[0][0] + i * 2048 + wave * 512);
            long nr = bn0 + row;
            gl_lds16(&Bt[nr * K + kt + scol], &Bs[0][0] + i * 2048 + wave * 512);
        }
        __syncthreads();
#pragma unroll
        for (int kk = 0; kk < 2; kk++) {
            bf16x8 af[4], bfr[4];
#pragma unroll
            for (int mi = 0; mi < 4; mi++)
                af[mi] = *(const bf16x8*)&As[wm + mi * 16 + lr][kk * 32 + lh * 8];
#pragma unroll
            for (int ni = 0; ni < 4; ni++)
                bfr[ni] = *(const bf16x8*)&Bs[wn + ni * 16 + lr][kk * 32 + lh * 8];
#pragma unroll
            for (int mi = 0; mi < 4; mi++)
#pragma unroll
                for (int ni = 0; ni < 4; ni++)
                    acc[mi][ni] = __builtin_amdgcn_mfma_f32_16x16x32_bf16(
                        af[mi], bfr[ni], acc[mi][ni], 0, 0, 0);
        }
    }

#pragma unroll
    for (int mi = 0; mi < 4; mi++)
#pragma unroll
        for (int ni = 0; ni < 4; ni++)
#pragma unroll
            for (int r2 = 0; r2 < 4; r2++) {
                int m = bm0 + wm + mi * 16 + lh * 4 + r2;
                if (m < M) {
                    int nc = bn0 + wn + ni * 16 + lr;
                    float v = acc[mi][ni][r2];
                    if (OUTF) ((float*)Cv)[(size_t)m * N + nc] = v + bias[nc];
                    else      ((u16*)Cv)[(size_t)m * N + nc] = f2bf(v);
                }
            }
}

// ---------------- fused V-QKV GEMM with attention epilogues ----------------
// C-tile = xb_V[40960][512] @ WvT[1536][512]^T. Grid (12, 320).
// n-section: 0=Q (va-attention fused, writes cat V-rows), 1=K (scores -> pglob),
// 2=V (writes compact vv[40960][512]).
// Each block = one bt (batch-token); each wave's 64-col span = one head.
// Register discipline (round-8 lesson): epilogue operands (qa/ka/va) live in
// LDS (attL), NOT registers — keeps VGPR below the 128 occupancy step.
__global__ __launch_bounds__(256) void gemm_qkv(const u16* __restrict__ A,
                                                const u16* __restrict__ Bt,
                                                const u16* __restrict__ aqkv,
                                                const float* __restrict__ mask,
                                                u16* __restrict__ vv,
                                                float* __restrict__ pglob,
                                                u16* __restrict__ cat) {
    __shared__ u16 As[128][64];
    __shared__ u16 Bs[128][64];
    __shared__ float attL[2][5][128];   // [0]=qa|ka, [1]=va (block n-range cols)
    const int t = threadIdx.x;
    const int bn0 = blockIdx.x * 128;
    const int bm0 = blockIdx.y * 128;
    const int wave = t >> 6, lane = t & 63;
    const int wm = (wave >> 1) * 64, wn = (wave & 1) * 64;
    const int lr = lane & 15, lh = lane >> 4;
    const int srow = wave * 8 + (lane >> 3);
    const int scol = (lane & 7) * 8;

    f32x4 acc[4][4] = {};

    for (int kt = 0; kt < 512; kt += 64) {
        __syncthreads();
#pragma unroll
        for (int i = 0; i < 4; i++) {
            int row = i * 32 + srow;
            int r = bm0 + row;
            long g = (long)(r >> 8) * 257 + (r & 255) + 1;   // V rows of x
            gl_lds16(&A[g * 512 + kt + scol], &As[0][0] + i * 2048 + wave * 512);
            long nr = bn0 + row;
            gl_lds16(&Bt[nr * 512 + kt + scol], &Bs[0][0] + i * 2048 + wave * 512);
        }
        __syncthreads();
#pragma unroll
        for (int kk = 0; kk < 2; kk++) {
            bf16x8 af[4], bfr[4];
#pragma unroll
            for (int mi = 0; mi < 4; mi++)
                af[mi] = *(const bf16x8*)&As[wm + mi * 16 + lr][kk * 32 + lh * 8];
#pragma unroll
            for (int ni = 0; ni < 4; ni++)
                bfr[ni] = *(const bf16x8*)&Bs[wn + ni * 16 + lr][kk * 32 + lh * 8];
#pragma unroll
            for (int mi = 0; mi < 4; mi++)
#pragma unroll
                for (int ni = 0; ni < 4; ni++)
                    acc[mi][ni] = __builtin_amdgcn_mfma_f32_16x16x32_bf16(
                        af[mi], bfr[ni], acc[mi][ni], 0, 0, 0);
        }
    }

    const int bt   = bm0 >> 8;                    // 0..159, uniform per block
    const int sec  = bn0 >> 9;                    // 0=Q, 1=K, 2=V
    const int nbase = bn0 & 511;
    const int head = (nbase + wn) >> 6;           // 0..7, uniform per wave
    const int b5   = bt / 5, t5 = bt - b5 * 5;
    const int jb   = (bm0 & 255) + wm;            // wave row base j (0..192)

    if (sec == 2) {
#pragma unroll
        for (int mi = 0; mi < 4; mi++)
#pragma unroll
            for (int ni = 0; ni < 4; ni++)
#pragma unroll
                for (int r2 = 0; r2 < 4; r2++) {
                    int r = bt * 256 + jb + mi * 16 + lh * 4 + r2;
                    vv[(size_t)r * 512 + nbase + wn + ni * 16 + lr] = f2bf(acc[mi][ni][r2]);
                }
        return;
    }

    // stage attention operands for this block's 128-col range into LDS
    {
        const int aoff = (sec == 1) ? 0 : 512;    // K-epi: qa; Q-epi: ka
        for (int ii = t; ii < 640; ii += 256) {
            int q = ii >> 7, col = ii & 127;
            attL[0][q][col] = bf2f(aqkv[(size_t)(b5 * 5 + q) * 1536 + aoff + nbase + col]);
            if (sec == 0)
                attL[1][q][col] = bf2f(aqkv[(size_t)(b5 * 5 + q) * 1536 + 1024 + nbase + col]);
        }
    }
    __syncthreads();

    if (sec == 1) {
        // scores: pglob[(b5*8+head)*5+q][t5*256 + j] = 0.125 * dot(kv_row, qa_q)
        // q sequential: one f32x4 live, weights from LDS (broadcast within lh groups)
#pragma unroll
        for (int q = 0; q < 5; q++) {
            float w0 = attL[0][q][wn + lr];
            float w1 = attL[0][q][wn + 16 + lr];
            float w2 = attL[0][q][wn + 32 + lr];
            float w3 = attL[0][q][wn + 48 + lr];
#pragma unroll
            for (int mi = 0; mi < 4; mi++) {
                f32x4 sc = acc[mi][0] * w0 + acc[mi][1] * w1 + acc[mi][2] * w2 + acc[mi][3] * w3;
#pragma unroll
                for (int off = 1; off < 16; off <<= 1)
#pragma unroll
                    for (int c = 0; c < 4; c++)
                        sc[c] += __shfl_xor(sc[c], off);
                if (lr == q) {
                    const int j0 = jb + mi * 16 + lh * 4;
                    *(f32x4*)&pglob[((size_t)(b5 * 8 + head) * 5 + q) * 1280 + t5 * 256 + j0] =
                        sc * 0.125f;
                }
            }
        }
    } else {
        // va attention: per row, 5 scores vs ka, mask+scale, softmax5, @ va -> cat
#pragma unroll
        for (int mi = 0; mi < 4; mi++) {
            f32x4 sc[5];
#pragma unroll
            for (int q = 0; q < 5; q++) {
                sc[q] = acc[mi][0] * attL[0][q][wn + lr]
                      + acc[mi][1] * attL[0][q][wn + 16 + lr]
                      + acc[mi][2] * attL[0][q][wn + 32 + lr]
                      + acc[mi][3] * attL[0][q][wn + 48 + lr];
            }
#pragma unroll
            for (int off = 1; off < 16; off <<= 1)
#pragma unroll
                for (int q = 0; q < 5; q++)
#pragma unroll
                    for (int c = 0; c < 4; c++)
                        sc[q][c] += __shfl_xor(sc[q][c], off);
            const int j0 = jb + mi * 16 + lh * 4;
            f32x4 mv;
#pragma unroll
            for (int c = 0; c < 4; c++) mv[c] = mask[bt * 256 + j0 + c] * 0.125f;
#pragma unroll
            for (int q = 0; q < 5; q++) sc[q] *= mv;
            f32x4 mx = sc[0];
#pragma unroll
            for (int q = 1; q < 5; q++)
#pragma unroll
                for (int c = 0; c < 4; c++) mx[c] = fmaxf(mx[c], sc[q][c]);
            f32x4 se = {};
#pragma unroll
            for (int q = 0; q < 5; q++) {
#pragma unroll
                for (int c = 0; c < 4; c++) sc[q][c] = __expf(sc[q][c] - mx[c]);
                se += sc[q];
            }
#pragma unroll
            for (int c = 0; c < 4; c++) se[c] = 1.f / se[c];
#pragma unroll
            for (int q = 0; q < 5; q++) sc[q] *= se;
#pragma unroll
            for (int ni = 0; ni < 4; ni++) {
                f32x4 o = sc[0] * attL[1][0][wn + ni * 16 + lr];
#pragma unroll
                for (int q = 1; q < 5; q++) o += sc[q] * attL[1][q][wn + ni * 16 + lr];
#pragma unroll
                for (int r2 = 0; r2 < 4; r2++) {
                    size_t g = (size_t)bt * 257 + 1 + j0 + r2;
                    cat[g * 512 + head * 64 + ni * 16 + lr] = f2bf(o[r2]);
                }
            }
        }
    }
}

// --- softmax in place over pglob rows. wave-per-row; grid 320 x 256 thr ---
__global__ __launch_bounds__(256) void av_softmax(float* __restrict__ pglob) {
    const int wave = threadIdx.x >> 6, lane = threadIdx.x & 63;
    const int rid = blockIdx.x * 4 + wave;
    float* row = pglob + (size_t)rid * 1280;
    float v[20];
    float mx = -3.4e38f;
#pragma unroll
    for (int i = 0; i < 20; i++) {
        v[i] = row[lane + i * 64];
        mx = fmaxf(mx, v[i]);
    }
#pragma unroll
    for (int off = 32; off > 0; off >>= 1) mx = fmaxf(mx, __shfl_xor(mx, off));
    float sum = 0.f;
#pragma unroll
    for (int i = 0; i < 20; i++) {
        v[i] = __expf(v[i] - mx);
        sum += v[i];
    }
#pragma unroll
    for (int off = 32; off > 0; off >>= 1) sum += __shfl_xor(sum, off);
    const float inv = 1.f / sum;
#pragma unroll
    for (int i = 0; i < 20; i++) row[lane + i * 64] = v[i] * inv;
}

// --- PV partials. grid 2048 = (bh)(256) x jc(8); 320 thr, wave=q, lane=d ---
__global__ __launch_bounds__(320) void av_pv(const u16* __restrict__ vv,
                                             const float* __restrict__ pglob,
                                             float* __restrict__ avpart) {
    __shared__ float pl[5][5][32];   // [q][t5][jj]
    const int blk = blockIdx.x;
    const int jc = blk & 7;
    const int bh = blk >> 3;
    const int bi = bh >> 3, hd = bh & 7;
    const int t = threadIdx.x;
    for (int ii = t; ii < 800; ii += 320) {
        int q = ii / 160, rem = ii - q * 160;
        int tt = rem >> 5, jj = rem & 31;
        pl[q][tt][jj] = pglob[((size_t)bh * 5 + q) * 1280 + tt * 256 + jc * 32 + jj];
    }
    __syncthreads();
    const int wave = t >> 6, lane = t & 63;   // wave = q
    float acc = 0.f;
    const int j0 = jc * 32;
    for (int jj = 0; jj < 32; jj++) {
#pragma unroll
        for (int t5 = 0; t5 < 5; t5++) {
            float v = bf2f(vv[((size_t)((bi * 5 + t5) * 256 + j0 + jj)) * 512 + hd * 64 + lane]);
            acc += pl[wave][t5][jj] * v;
        }
    }
    avpart[((size_t)jc * 1280 + (size_t)bh * 5 + wave) * 64 + lane] = acc;
}

// --- reduce partials -> cat A-rows. grid 320 x 256 thr ---
__global__ __launch_bounds__(256) void av_write(const float* __restrict__ avpart,
                                                u16* __restrict__ cat) {
    const int idx = blockIdx.x * 256 + threadIdx.x;
    const int d = idx & 63;
    const int r = idx >> 6;                   // 0..1279 = bh*5+q
    const int q = r % 5, bh = r / 5;
    const int bi = bh >> 3, hd = bh & 7;
    float s = 0.f;
#pragma unroll
    for (int jc = 0; jc < 8; jc++) s += avpart[((size_t)jc * 1280 + r) * 64 + d];
    cat[(size_t)((bi * 5 + q) * 257) * 512 + hd * 64 + d] = f2bf(s);
}

extern "C" void kernel_launch(void* const* d_in, const int* in_sizes, int n_in,
                              void* d_out, int out_size, void* d_ws, size_t ws_size,
                              hipStream_t stream) {
    const float* x    = (const float*)d_in[0];  // (160,257,512) f32
    const float* mask = (const float*)d_in[1];  // (160,256) f32
    const float* Wv   = (const float*)d_in[2];  // (512,1536) f32
    const float* Wa   = (const float*)d_in[3];  // (512,1536) f32
    const float* Wo   = (const float*)d_in[4];  // (512,512) f32
    const float* bo   = (const float*)d_in[5];  // (512,) f32
    float* out = (float*)d_out;

    char* ws = (char*)d_ws;
    u16*   xb     = (u16*)(ws);                   // 42,106,880 B
    u16*   WvT    = (u16*)(ws + 42106880);        //  1,572,864 B
    u16*   WaT    = (u16*)(ws + 43679744);        //  1,572,864 B
    u16*   WoT    = (u16*)(ws + 45252608);        //    524,288 B
    u16*   aqkv   = (u16*)(ws + 45776896);        //    491,520 B
    u16*   vv     = (u16*)(ws + 46268416);        // 41,943,040 B
    u16*   cat    = (u16*)(ws + 88211456);        // 42,106,880 B
    float* pglob  = (float*)(ws + 130318336);     //  6,553,600 B
    float* avpart = (float*)(ws + 136871936);     //  2,621,440 B -> ~139.5 MB

    prep<<<dim3(10728), 256, 0, stream>>>(x, Wv, Wa, Wo, xb, WvT, WaT, WoT);

    // a_qkv = A @ Wa_qkv (must precede gemm_qkv: its epilogues read aqkv)
    gemm_k<2, 0><<<dim3(12, 2), 256, 0, stream>>>(xb, WaT, aqkv, nullptr, 160, 1536, 512);

    // V-QKV GEMM with fused attention epilogues
    gemm_qkv<<<dim3(12, 320), 256, 0, stream>>>(xb, WvT, aqkv, mask, vv, pglob, cat);

    av_softmax<<<dim3(320), 256, 0, stream>>>(pglob);
    av_pv<<<dim3(2048), 320, 0, stream>>>(vv, pglob, avpart);
    av_write<<<dim3(320), 256, 0, stream>>>(avpart, cat);

    // out = cat @ Wo + bo   (float out)
    gemm_k<0, 1><<<dim3(4, 322), 256, 0, stream>>>(cat, WoT, out, bo, 41120, 512, 512);
}

// Round 11
// 257.058 us; speedup vs baseline: 1.4360x; 1.4360x over previous
//
#include <hip/hip_runtime.h>
#include <hip/hip_bf16.h>

typedef unsigned short u16;
typedef __bf16 bf16x8 __attribute__((ext_vector_type(8)));
typedef u16 u16x8 __attribute__((ext_vector_type(8)));
typedef float f32x4 __attribute__((ext_vector_type(4)));

__device__ __forceinline__ float bf2f(u16 u) {
    return __uint_as_float(((unsigned)u) << 16);
}
__device__ __forceinline__ u16 f2bf(float f) {
    unsigned u = __float_as_uint(f);
    unsigned r = (u + 0x7fffu + ((u >> 16) & 1u)) >> 16;
    return (u16)r;
}

// async global->LDS, 16B per lane. dst is wave-uniform base; HW adds lane*16.
__device__ __forceinline__ void gl_lds16(const u16* g, u16* l) {
    __builtin_amdgcn_global_load_lds(
        (const __attribute__((address_space(1))) void*)g,
        (__attribute__((address_space(3))) void*)l, 16, 0, 0);
}

// ---------------- fused prep: x f32->bf16 convert + 3 weight transposes ----------------
__global__ __launch_bounds__(256) void prep(const float* __restrict__ x,
                                            const float* __restrict__ Wv,
                                            const float* __restrict__ Wa,
                                            const float* __restrict__ Wo,
                                            u16* __restrict__ xb,
                                            u16* __restrict__ WvT,
                                            u16* __restrict__ WaT,
                                            u16* __restrict__ WoT) {
    __shared__ float tile[64][65];
    int blk = blockIdx.x;
    if (blk < 10280) {
        int i = (blk * 256 + threadIdx.x) * 8;
        float4 a = *(const float4*)&x[i];
        float4 b = *(const float4*)&x[i + 4];
        u16x8 o;
        o[0] = f2bf(a.x); o[1] = f2bf(a.y); o[2] = f2bf(a.z); o[3] = f2bf(a.w);
        o[4] = f2bf(b.x); o[5] = f2bf(b.y); o[6] = f2bf(b.z); o[7] = f2bf(b.w);
        *(u16x8*)&xb[i] = o;
        return;
    }
    blk -= 10280;
    const float* W; u16* WT; int N;
    if (blk < 192)      { W = Wv; WT = WvT; N = 1536; }
    else if (blk < 384) { W = Wa; WT = WaT; N = 1536; blk -= 192; }
    else                { W = Wo; WT = WoT; N = 512;  blk -= 384; }
    const int K = 512;
    const int nt = N >> 6;
    const int k0 = (blk / nt) << 6;
    const int n0 = (blk % nt) << 6;
    for (int i = threadIdx.x; i < 4096; i += 256) {
        int r = i >> 6, c = i & 63;
        tile[r][c] = W[(size_t)(k0 + r) * N + n0 + c];
    }
    __syncthreads();
    for (int i = threadIdx.x; i < 4096; i += 256) {
        int r = i >> 6, c = i & 63;
        WT[(size_t)(n0 + r) * K + k0 + c] = f2bf(tile[c][r]);
    }
}

// ---------------- small m97-style GEMM (A-projection only) ----------
template <int MODE, int OUTF>
__global__ __launch_bounds__(256) void gemm_k(const u16* __restrict__ A,
                                              const u16* __restrict__ Bt,
                                              void* __restrict__ Cv,
                                              const float* __restrict__ bias,
                                              int M, int N, int K) {
    __shared__ u16 As[128][64];
    __shared__ u16 Bs[128][64];
    const int t = threadIdx.x;
    const int bn0 = blockIdx.x * 128;
    const int bm0 = blockIdx.y * 128;
    const int wave = t >> 6, lane = t & 63;
    const int wm = (wave >> 1) * 64, wn = (wave & 1) * 64;
    const int lr = lane & 15, lh = lane >> 4;
    const int srow = wave * 8 + (lane >> 3);
    const int scol = (lane & 7) * 8;

    f32x4 acc[4][4] = {};

    for (int kt = 0; kt < K; kt += 64) {
        __syncthreads();
#pragma unroll
        for (int i = 0; i < 4; i++) {
            int row = i * 32 + srow;
            int r = bm0 + row;
            long g;
            if (MODE == 0) g = (r < M) ? (long)r : 0l;
            else           g = (r < M) ? (long)r * 257 : 0l;
            gl_lds16(&A[g * K + kt + scol], &As[0][0] + i * 2048 + wave * 512);
            long nr = bn0 + row;
            gl_lds16(&Bt[nr * K + kt + scol], &Bs[0][0] + i * 2048 + wave * 512);
        }
        __syncthreads();
#pragma unroll
        for (int kk = 0; kk < 2; kk++) {
            bf16x8 af[4], bfr[4];
#pragma unroll
            for (int mi = 0; mi < 4; mi++)
                af[mi] = *(const bf16x8*)&As[wm + mi * 16 + lr][kk * 32 + lh * 8];
#pragma unroll
            for (int ni = 0; ni < 4; ni++)
                bfr[ni] = *(const bf16x8*)&Bs[wn + ni * 16 + lr][kk * 32 + lh * 8];
#pragma unroll
            for (int mi = 0; mi < 4; mi++)
#pragma unroll
                for (int ni = 0; ni < 4; ni++)
                    acc[mi][ni] = __builtin_amdgcn_mfma_f32_16x16x32_bf16(
                        af[mi], bfr[ni], acc[mi][ni], 0, 0, 0);
        }
    }

#pragma unroll
    for (int mi = 0; mi < 4; mi++)
#pragma unroll
        for (int ni = 0; ni < 4; ni++)
#pragma unroll
            for (int r2 = 0; r2 < 4; r2++) {
                int m = bm0 + wm + mi * 16 + lh * 4 + r2;
                if (m < M) {
                    int nc = bn0 + wn + ni * 16 + lr;
                    float v = acc[mi][ni][r2];
                    if (OUTF) ((float*)Cv)[(size_t)m * N + nc] = v + bias[nc];
                    else      ((u16*)Cv)[(size_t)m * N + nc] = f2bf(v);
                }
            }
}

// ---------------- pipelined 256x256 GEMM, K=512 fixed ----------------
// 1024 threads = 16 waves. Double-buffered 128KB LDS; counted vmcnt(4) keeps
// next tile's loads in flight across raw s_barrier (T4). T2 XOR swizzle:
// linear gl_lds dest + inverse-swizzled global source + swizzled ds_read
// (rule #21). Prologue pinned with sched_barrier + vmcnt(0) so "oldest 4"
// accounting can't be broken by compiler interleaving the two stage calls.
template <int MODE, int OUTF>
__global__ __launch_bounds__(1024) void gemm_big(const u16* __restrict__ A,
                                                 const u16* __restrict__ Bt,
                                                 void* __restrict__ Cv,
                                                 const float* __restrict__ bias,
                                                 int M, int N) {
    __shared__ u16 As[2][256][64];
    __shared__ u16 Bs[2][256][64];
    const int t = threadIdx.x;
    const int bn0 = blockIdx.x * 256;
    const int bm0 = blockIdx.y * 256;
    const int wave = t >> 6, lane = t & 63;
    const int wm = (wave >> 2) * 64, wn = (wave & 3) * 64;
    const int lr = lane & 15, lh = lane >> 4;
    const int xr = (lr & 7) << 3;             // read-side swizzle (row&7 == lr&7)
    u16* AsF = &As[0][0][0];
    u16* BsF = &Bs[0][0][0];

    // staging: chunk c = j*1024 + wave*64 + lane; row = c>>3 (row&7 == lane>>3),
    // linear LDS seg = lane&7, global seg = (lane&7)^(lane>>3) (inverse swizzle).
    const int gsa = ((lane & 7) ^ (lane >> 3)) * 8;
    auto stage = [&](int buf, int kt_) {
        const int kc = kt_ * 64;
#pragma unroll
        for (int j = 0; j < 2; j++) {
            int c0 = j * 1024 + wave * 64;
            int row = (c0 + lane) >> 3;
            int r = bm0 + row;
            long ga;
            if (MODE == 0) ga = (r < M) ? (long)r : 0l;
            else           ga = (long)(r >> 8) * 257 + (r & 255) + 1;
            gl_lds16(&A[ga * 512 + kc + gsa], AsF + buf * 16384 + c0 * 8);
            gl_lds16(&Bt[(long)(bn0 + row) * 512 + kc + gsa], BsF + buf * 16384 + c0 * 8);
        }
    };

    f32x4 acc[4][4] = {};

    stage(0, 0);
    __builtin_amdgcn_sched_barrier(0);
    stage(1, 1);
    __builtin_amdgcn_sched_barrier(0);
    asm volatile("s_waitcnt vmcnt(0)" ::: "memory");   // conservative: both tiles done
    __builtin_amdgcn_s_barrier();
    __builtin_amdgcn_sched_barrier(0);

    int cur = 0;
    for (int kt = 0; kt < 8; kt++) {
        __builtin_amdgcn_s_setprio(1);
#pragma unroll
        for (int kk = 0; kk < 2; kk++) {
            bf16x8 af[4], bfr[4];
#pragma unroll
            for (int mi = 0; mi < 4; mi++)
                af[mi] = *(const bf16x8*)&As[cur][wm + mi * 16 + lr][(kk * 32 + lh * 8) ^ xr];
#pragma unroll
            for (int ni = 0; ni < 4; ni++)
                bfr[ni] = *(const bf16x8*)&Bs[cur][wn + ni * 16 + lr][(kk * 32 + lh * 8) ^ xr];
#pragma unroll
            for (int mi = 0; mi < 4; mi++)
#pragma unroll
                for (int ni = 0; ni < 4; ni++)
                    acc[mi][ni] = __builtin_amdgcn_mfma_f32_16x16x32_bf16(
                        af[mi], bfr[ni], acc[mi][ni], 0, 0, 0);
        }
        __builtin_amdgcn_s_setprio(0);
        if (kt == 7) break;
        __builtin_amdgcn_sched_barrier(0);
        __builtin_amdgcn_s_barrier();            // all waves done reading buf[cur]
        __builtin_amdgcn_sched_barrier(0);
        if (kt + 2 < 8) {
            stage(cur, kt + 2);                  // refill buf[cur], 4 loads in flight
            __builtin_amdgcn_sched_barrier(0);
            asm volatile("s_waitcnt vmcnt(4)" ::: "memory");   // prev tile only
        } else {
            asm volatile("s_waitcnt vmcnt(0)" ::: "memory");
        }
        __builtin_amdgcn_sched_barrier(0);
        __builtin_amdgcn_s_barrier();            // buf[cur^1] ready for all waves
        __builtin_amdgcn_sched_barrier(0);
        cur ^= 1;
    }

#pragma unroll
    for (int mi = 0; mi < 4; mi++)
#pragma unroll
        for (int ni = 0; ni < 4; ni++)
#pragma unroll
            for (int r2 = 0; r2 < 4; r2++) {
                int m = bm0 + wm + mi * 16 + lh * 4 + r2;
                if (m < M) {
                    int nc = bn0 + wn + ni * 16 + lr;
                    float v = acc[mi][ni][r2];
                    if (OUTF) ((float*)Cv)[(size_t)m * N + nc] = v + bias[nc];
                    else      ((u16*)Cv)[(size_t)m * N + nc] = f2bf(v);
                }
            }
}

// ============ attention av, 4-kernel decomposition (round-6 verified) ==========
// pglob layout: row rid = (bi*8+hd)*5+q, col s = j*5 + t5  (written by av_scores,
// consumed by av_pv with the SAME mapping — round-10's mismatch fixed).

__global__ __launch_bounds__(256) void av_scores(const u16* __restrict__ vqkv,
                                                 const u16* __restrict__ aqkv,
                                                 float* __restrict__ pglob) {
    __shared__ float qa[5][64];
    const int blk = blockIdx.x;
    const int chunk = blk % 5;
    const int bh = blk / 5;
    const int bi = bh >> 3, hd = bh & 7;
    const int t = threadIdx.x;
    for (int i = t; i < 320; i += 256) {
        int tt = i >> 6, d = i & 63;
        qa[tt][d] = bf2f(aqkv[(size_t)(bi * 5 + tt) * 1536 + hd * 64 + d]);
    }
    __syncthreads();
    const int s = chunk * 256 + t;
    const int j = s / 5, t5 = s - j * 5;
    const u16* krow = &vqkv[(size_t)((bi * 5 + t5) * 256 + j) * 1536 + 512 + hd * 64];
    float a0 = 0, a1 = 0, a2 = 0, a3 = 0, a4 = 0;
#pragma unroll
    for (int d = 0; d < 64; d += 8) {
        u16x8 v8 = *(const u16x8*)&krow[d];
#pragma unroll
        for (int jj = 0; jj < 8; jj++) {
            float f = bf2f(v8[jj]);
            a0 += f * qa[0][d + jj];
            a1 += f * qa[1][d + jj];
            a2 += f * qa[2][d + jj];
            a3 += f * qa[3][d + jj];
            a4 += f * qa[4][d + jj];
        }
    }
    const size_t base = (size_t)bh * 5 * 1280 + s;
    pglob[base]        = a0 * 0.125f;
    pglob[base + 1280] = a1 * 0.125f;
    pglob[base + 2560] = a2 * 0.125f;
    pglob[base + 3840] = a3 * 0.125f;
    pglob[base + 5120] = a4 * 0.125f;
}

__global__ __launch_bounds__(256) void av_softmax(float* __restrict__ pglob) {
    const int wave = threadIdx.x >> 6, lane = threadIdx.x & 63;
    const int rid = blockIdx.x * 4 + wave;
    float* row = pglob + (size_t)rid * 1280;
    float v[20];
    float mx = -3.4e38f;
#pragma unroll
    for (int i = 0; i < 20; i++) {
        v[i] = row[lane + i * 64];
        mx = fmaxf(mx, v[i]);
    }
#pragma unroll
    for (int off = 32; off > 0; off >>= 1) mx = fmaxf(mx, __shfl_xor(mx, off));
    float sum = 0.f;
#pragma unroll
    for (int i = 0; i < 20; i++) {
        v[i] = __expf(v[i] - mx);
        sum += v[i];
    }
#pragma unroll
    for (int off = 32; off > 0; off >>= 1) sum += __shfl_xor(sum, off);
    const float inv = 1.f / sum;
#pragma unroll
    for (int i = 0; i < 20; i++) row[lane + i * 64] = v[i] * inv;
}

// --- PV partials. grid 2048 = (bh)(256) x jc(8); 320 thr, wave=q, lane=d ---
// round-6 layout: pl[q][i], i = jj*5 + t5 over cols [jc*160, jc*160+160)
__global__ __launch_bounds__(320) void av_pv(const u16* __restrict__ vqkv,
                                             const float* __restrict__ pglob,
                                             float* __restrict__ avpart) {
    __shared__ float pl[5][160];
    const int blk = blockIdx.x;
    const int jc = blk & 7;
    const int bh = blk >> 3;
    const int bi = bh >> 3, hd = bh & 7;
    const int t = threadIdx.x;
    for (int ii = t; ii < 800; ii += 320) {
        int q = ii / 160, i = ii - q * 160;
        pl[q][i] = pglob[((size_t)bh * 5 + q) * 1280 + jc * 160 + i];
    }
    __syncthreads();
    const int wave = t >> 6, lane = t & 63;   // wave = q
    float acc = 0.f;
    const int j0 = jc * 32;
    for (int jj = 0; jj < 32; jj++) {
        const int j = j0 + jj;
#pragma unroll
        for (int t5 = 0; t5 < 5; t5++) {
            float v = bf2f(vqkv[(size_t)((bi * 5 + t5) * 256 + j) * 1536 + 1024 + hd * 64 + lane]);
            acc += pl[wave][jj * 5 + t5] * v;
        }
    }
    avpart[((size_t)jc * 1280 + (size_t)bh * 5 + wave) * 64 + lane] = acc;
}

__global__ __launch_bounds__(256) void av_write(const float* __restrict__ avpart,
                                                u16* __restrict__ cat) {
    const int idx = blockIdx.x * 256 + threadIdx.x;
    const int d = idx & 63;
    const int r = idx >> 6;
    const int q = r % 5, bh = r / 5;
    const int bi = bh >> 3, hd = bh & 7;
    float s = 0.f;
#pragma unroll
    for (int jc = 0; jc < 8; jc++) s += avpart[((size_t)jc * 1280 + r) * 64 + d];
    cat[(size_t)((bi * 5 + q) * 257) * 512 + hd * 64 + d] = f2bf(s);
}

// ---------------- attention va: thread-per-query (round-6 verified) ----------------
__global__ __launch_bounds__(256) void attn_va(const u16* __restrict__ vqkv,
                                               const u16* __restrict__ aqkv,
                                               const float* __restrict__ mask,
                                               u16* __restrict__ cat) {
    __shared__ float ka[5][64], vaS[5][64];
    const int blk = blockIdx.x;
    const int chunk = blk % 5;
    const int bh = blk / 5;
    const int bi = bh >> 3, hd = bh & 7;
    const int t = threadIdx.x;
    for (int i = t; i < 320; i += 256) {
        int tt = i >> 6, d = i & 63;
        ka[tt][d]  = bf2f(aqkv[(size_t)(bi * 5 + tt) * 1536 + 512 + hd * 64 + d]);
        vaS[tt][d] = bf2f(aqkv[(size_t)(bi * 5 + tt) * 1536 + 1024 + hd * 64 + d]);
    }
    __syncthreads();
    const int s = chunk * 256 + t;
    const int j = s / 5, t5 = s - j * 5;
    const int row = (bi * 5 + t5) * 256 + j;
    const u16* qrow = &vqkv[(size_t)row * 1536 + hd * 64];
    float r0 = 0, r1 = 0, r2 = 0, r3 = 0, r4 = 0;
#pragma unroll
    for (int d = 0; d < 64; d += 8) {
        u16x8 q8 = *(const u16x8*)&qrow[d];
#pragma unroll
        for (int jj = 0; jj < 8; jj++) {
            float f = bf2f(q8[jj]);
            r0 += f * ka[0][d + jj];
            r1 += f * ka[1][d + jj];
            r2 += f * ka[2][d + jj];
            r3 += f * ka[3][d + jj];
            r4 += f * ka[4][d + jj];
        }
    }
    const float mval = mask[row] * 0.125f;
    r0 *= mval; r1 *= mval; r2 *= mval; r3 *= mval; r4 *= mval;
    float mx = fmaxf(fmaxf(fmaxf(r0, r1), fmaxf(r2, r3)), r4);
    float e0 = __expf(r0 - mx), e1 = __expf(r1 - mx), e2 = __expf(r2 - mx);
    float e3 = __expf(r3 - mx), e4 = __expf(r4 - mx);
    const float inv = 1.f / (e0 + e1 + e2 + e3 + e4);
    e0 *= inv; e1 *= inv; e2 *= inv; e3 *= inv; e4 *= inv;
    const size_t orow = ((size_t)((bi * 5 + t5) * 257) + 1 + j) * 512 + hd * 64;
#pragma unroll
    for (int d = 0; d < 64; d += 8) {
        u16x8 o8;
#pragma unroll
        for (int jj = 0; jj < 8; jj++) {
            float o = e0 * vaS[0][d + jj] + e1 * vaS[1][d + jj] + e2 * vaS[2][d + jj] +
                      e3 * vaS[3][d + jj] + e4 * vaS[4][d + jj];
            o8[jj] = f2bf(o);
        }
        *(u16x8*)&cat[orow + d] = o8;
    }
}

extern "C" void kernel_launch(void* const* d_in, const int* in_sizes, int n_in,
                              void* d_out, int out_size, void* d_ws, size_t ws_size,
                              hipStream_t stream) {
    const float* x    = (const float*)d_in[0];  // (160,257,512) f32
    const float* mask = (const float*)d_in[1];  // (160,256) f32
    const float* Wv   = (const float*)d_in[2];  // (512,1536) f32
    const float* Wa   = (const float*)d_in[3];  // (512,1536) f32
    const float* Wo   = (const float*)d_in[4];  // (512,512) f32
    const float* bo   = (const float*)d_in[5];  // (512,) f32
    float* out = (float*)d_out;

    char* ws = (char*)d_ws;
    u16* xb   = (u16*)(ws);                   // 42,106,880 B
    u16* WvT  = (u16*)(ws + 42106880);        //  1,572,864 B
    u16* WaT  = (u16*)(ws + 43679744);        //  1,572,864 B
    u16* WoT  = (u16*)(ws + 45252608);        //    524,288 B
    u16* aqkv = (u16*)(ws + 45776896);        //    491,520 B
    u16* vqkv = (u16*)(ws + 46268416);        // 125,829,120 B
    u16* cat  = (u16*)(ws + 172097536);       // 42,106,880 B  -> ~214.2 MB
    // xb is dead after the projection GEMMs; reuse as av scratch:
    float* pglob  = (float*)(ws);             // 6,553,600 B
    float* avpart = (float*)(ws + 6553600);   // 2,621,440 B

    prep<<<dim3(10728), 256, 0, stream>>>(x, Wv, Wa, Wo, xb, WvT, WaT, WoT);

    // a_qkv = A @ Wa_qkv
    gemm_k<2, 0><<<dim3(12, 2), 256, 0, stream>>>(xb, WaT, aqkv, nullptr, 160, 1536, 512);

    // v_qkv = V @ Wv_qkv  (pipelined 256^2; M=40960 exact multiple)
    gemm_big<1, 0><<<dim3(6, 160), 1024, 0, stream>>>(xb, WvT, vqkv, nullptr, 40960, 1536);

    av_scores<<<dim3(1280), 256, 0, stream>>>(vqkv, aqkv, pglob);
    av_softmax<<<dim3(320), 256, 0, stream>>>(pglob);
    av_pv<<<dim3(2048), 320, 0, stream>>>(vqkv, pglob, avpart);
    av_write<<<dim3(320), 256, 0, stream>>>(avpart, cat);

    attn_va<<<dim3(1280), 256, 0, stream>>>(vqkv, aqkv, mask, cat);

    // out = cat @ Wo + bo  (M=41120 -> 161 m-blocks, clamped)
    gemm_big<0, 1><<<dim3(2, 161), 1024, 0, stream>>>(cat, WoT, out, bo, 41120, 512);
}

// Round 12
// 254.135 us; speedup vs baseline: 1.4525x; 1.0115x over previous
//
#include <hip/hip_runtime.h>
#include <hip/hip_bf16.h>

typedef unsigned short u16;
typedef __bf16 bf16x8 __attribute__((ext_vector_type(8)));
typedef u16 u16x8 __attribute__((ext_vector_type(8)));
typedef float f32x4 __attribute__((ext_vector_type(4)));

__device__ __forceinline__ float bf2f(u16 u) {
    return __uint_as_float(((unsigned)u) << 16);
}
__device__ __forceinline__ u16 f2bf(float f) {
    unsigned u = __float_as_uint(f);
    unsigned r = (u + 0x7fffu + ((u >> 16) & 1u)) >> 16;
    return (u16)r;
}

// async global->LDS, 16B per lane. dst is wave-uniform base; HW adds lane*16.
__device__ __forceinline__ void gl_lds16(const u16* g, u16* l) {
    __builtin_amdgcn_global_load_lds(
        (const __attribute__((address_space(1))) void*)g,
        (__attribute__((address_space(3))) void*)l, 16, 0, 0);
}

// ---------------- fused prep: x f32->bf16 convert + 3 weight transposes ----------------
__global__ __launch_bounds__(256) void prep(const float* __restrict__ x,
                                            const float* __restrict__ Wv,
                                            const float* __restrict__ Wa,
                                            const float* __restrict__ Wo,
                                            u16* __restrict__ xb,
                                            u16* __restrict__ WvT,
                                            u16* __restrict__ WaT,
                                            u16* __restrict__ WoT) {
    __shared__ float tile[64][65];
    int blk = blockIdx.x;
    if (blk < 10280) {
        int i = (blk * 256 + threadIdx.x) * 8;
        float4 a = *(const float4*)&x[i];
        float4 b = *(const float4*)&x[i + 4];
        u16x8 o;
        o[0] = f2bf(a.x); o[1] = f2bf(a.y); o[2] = f2bf(a.z); o[3] = f2bf(a.w);
        o[4] = f2bf(b.x); o[5] = f2bf(b.y); o[6] = f2bf(b.z); o[7] = f2bf(b.w);
        *(u16x8*)&xb[i] = o;
        return;
    }
    blk -= 10280;
    const float* W; u16* WT; int N;
    if (blk < 192)      { W = Wv; WT = WvT; N = 1536; }
    else if (blk < 384) { W = Wa; WT = WaT; N = 1536; blk -= 192; }
    else                { W = Wo; WT = WoT; N = 512;  blk -= 384; }
    const int K = 512;
    const int nt = N >> 6;
    const int k0 = (blk / nt) << 6;
    const int n0 = (blk % nt) << 6;
    for (int i = threadIdx.x; i < 4096; i += 256) {
        int r = i >> 6, c = i & 63;
        tile[r][c] = W[(size_t)(k0 + r) * N + n0 + c];
    }
    __syncthreads();
    for (int i = threadIdx.x; i < 4096; i += 256) {
        int r = i >> 6, c = i & 63;
        WT[(size_t)(n0 + r) * K + k0 + c] = f2bf(tile[c][r]);
    }
}

// ---------------- small m97-style GEMM (A-projection only) ----------
template <int MODE, int OUTF>
__global__ __launch_bounds__(256) void gemm_k(const u16* __restrict__ A,
                                              const u16* __restrict__ Bt,
                                              void* __restrict__ Cv,
                                              const float* __restrict__ bias,
                                              int M, int N, int K) {
    __shared__ u16 As[128][64];
    __shared__ u16 Bs[128][64];
    const int t = threadIdx.x;
    const int bn0 = blockIdx.x * 128;
    const int bm0 = blockIdx.y * 128;
    const int wave = t >> 6, lane = t & 63;
    const int wm = (wave >> 1) * 64, wn = (wave & 1) * 64;
    const int lr = lane & 15, lh = lane >> 4;
    const int srow = wave * 8 + (lane >> 3);
    const int scol = (lane & 7) * 8;

    f32x4 acc[4][4] = {};

    for (int kt = 0; kt < K; kt += 64) {
        __syncthreads();
#pragma unroll
        for (int i = 0; i < 4; i++) {
            int row = i * 32 + srow;
            int r = bm0 + row;
            long g;
            if (MODE == 0) g = (r < M) ? (long)r : 0l;
            else           g = (r < M) ? (long)r * 257 : 0l;
            gl_lds16(&A[g * K + kt + scol], &As[0][0] + i * 2048 + wave * 512);
            long nr = bn0 + row;
            gl_lds16(&Bt[nr * K + kt + scol], &Bs[0][0] + i * 2048 + wave * 512);
        }
        __syncthreads();
#pragma unroll
        for (int kk = 0; kk < 2; kk++) {
            bf16x8 af[4], bfr[4];
#pragma unroll
            for (int mi = 0; mi < 4; mi++)
                af[mi] = *(const bf16x8*)&As[wm + mi * 16 + lr][kk * 32 + lh * 8];
#pragma unroll
            for (int ni = 0; ni < 4; ni++)
                bfr[ni] = *(const bf16x8*)&Bs[wn + ni * 16 + lr][kk * 32 + lh * 8];
#pragma unroll
            for (int mi = 0; mi < 4; mi++)
#pragma unroll
                for (int ni = 0; ni < 4; ni++)
                    acc[mi][ni] = __builtin_amdgcn_mfma_f32_16x16x32_bf16(
                        af[mi], bfr[ni], acc[mi][ni], 0, 0, 0);
        }
    }

#pragma unroll
    for (int mi = 0; mi < 4; mi++)
#pragma unroll
        for (int ni = 0; ni < 4; ni++)
#pragma unroll
            for (int r2 = 0; r2 < 4; r2++) {
                int m = bm0 + wm + mi * 16 + lh * 4 + r2;
                if (m < M) {
                    int nc = bn0 + wn + ni * 16 + lr;
                    float v = acc[mi][ni][r2];
                    if (OUTF) ((float*)Cv)[(size_t)m * N + nc] = v + bias[nc];
                    else      ((u16*)Cv)[(size_t)m * N + nc] = f2bf(v);
                }
            }
}

// ---------------- pipelined 256x256 GEMM, K=512 fixed ----------------
// round-11 verified (counted vmcnt(4), both-sides swizzle, 0 bank conflicts)
// + T1 bijective XCD-chunked block swizzle (m204): the column-blocks sharing
// an A m-panel land on one XCD's L2 (FETCH was 3x ideal without it).
template <int MODE, int OUTF>
__global__ __launch_bounds__(1024) void gemm_big(const u16* __restrict__ A,
                                                 const u16* __restrict__ Bt,
                                                 void* __restrict__ Cv,
                                                 const float* __restrict__ bias,
                                                 int M, int N) {
    __shared__ u16 As[2][256][64];
    __shared__ u16 Bs[2][256][64];
    const int t = threadIdx.x;
    // bijective XCD swizzle: dispatch slot orig (on XCD orig%8) runs logical
    // tile wgid; each XCD gets a contiguous chunk of logical tile space.
    const int nwg = gridDim.x * gridDim.y;
    const int orig = blockIdx.y * gridDim.x + blockIdx.x;
    const int qc = nwg >> 3, rc = nwg & 7;
    const int xcd = orig & 7, slot = orig >> 3;
    const int wgid = (xcd < rc ? xcd * (qc + 1) : rc * (qc + 1) + (xcd - rc) * qc) + slot;
    const int bn0 = (wgid % gridDim.x) * 256;
    const int bm0 = (wgid / gridDim.x) * 256;
    const int wave = t >> 6, lane = t & 63;
    const int wm = (wave >> 2) * 64, wn = (wave & 3) * 64;
    const int lr = lane & 15, lh = lane >> 4;
    const int xr = (lr & 7) << 3;             // read-side swizzle (row&7 == lr&7)
    u16* AsF = &As[0][0][0];
    u16* BsF = &Bs[0][0][0];

    // staging: chunk c = j*1024 + wave*64 + lane; row = c>>3 (row&7 == lane>>3),
    // linear LDS seg = lane&7, global seg = (lane&7)^(lane>>3) (inverse swizzle).
    const int gsa = ((lane & 7) ^ (lane >> 3)) * 8;
    auto stage = [&](int buf, int kt_) {
        const int kc = kt_ * 64;
#pragma unroll
        for (int j = 0; j < 2; j++) {
            int c0 = j * 1024 + wave * 64;
            int row = (c0 + lane) >> 3;
            int r = bm0 + row;
            long ga;
            if (MODE == 0) ga = (r < M) ? (long)r : 0l;
            else           ga = (long)(r >> 8) * 257 + (r & 255) + 1;
            gl_lds16(&A[ga * 512 + kc + gsa], AsF + buf * 16384 + c0 * 8);
            gl_lds16(&Bt[(long)(bn0 + row) * 512 + kc + gsa], BsF + buf * 16384 + c0 * 8);
        }
    };

    f32x4 acc[4][4] = {};

    stage(0, 0);
    __builtin_amdgcn_sched_barrier(0);
    stage(1, 1);
    __builtin_amdgcn_sched_barrier(0);
    asm volatile("s_waitcnt vmcnt(0)" ::: "memory");   // conservative: both tiles done
    __builtin_amdgcn_s_barrier();
    __builtin_amdgcn_sched_barrier(0);

    int cur = 0;
    for (int kt = 0; kt < 8; kt++) {
        __builtin_amdgcn_s_setprio(1);
#pragma unroll
        for (int kk = 0; kk < 2; kk++) {
            bf16x8 af[4], bfr[4];
#pragma unroll
            for (int mi = 0; mi < 4; mi++)
                af[mi] = *(const bf16x8*)&As[cur][wm + mi * 16 + lr][(kk * 32 + lh * 8) ^ xr];
#pragma unroll
            for (int ni = 0; ni < 4; ni++)
                bfr[ni] = *(const bf16x8*)&Bs[cur][wn + ni * 16 + lr][(kk * 32 + lh * 8) ^ xr];
#pragma unroll
            for (int mi = 0; mi < 4; mi++)
#pragma unroll
                for (int ni = 0; ni < 4; ni++)
                    acc[mi][ni] = __builtin_amdgcn_mfma_f32_16x16x32_bf16(
                        af[mi], bfr[ni], acc[mi][ni], 0, 0, 0);
        }
        __builtin_amdgcn_s_setprio(0);
        if (kt == 7) break;
        __builtin_amdgcn_sched_barrier(0);
        __builtin_amdgcn_s_barrier();            // all waves done reading buf[cur]
        __builtin_amdgcn_sched_barrier(0);
        if (kt + 2 < 8) {
            stage(cur, kt + 2);                  // refill buf[cur], 4 loads in flight
            __builtin_amdgcn_sched_barrier(0);
            asm volatile("s_waitcnt vmcnt(4)" ::: "memory");   // prev tile only
        } else {
            asm volatile("s_waitcnt vmcnt(0)" ::: "memory");
        }
        __builtin_amdgcn_sched_barrier(0);
        __builtin_amdgcn_s_barrier();            // buf[cur^1] ready for all waves
        __builtin_amdgcn_sched_barrier(0);
        cur ^= 1;
    }

#pragma unroll
    for (int mi = 0; mi < 4; mi++)
#pragma unroll
        for (int ni = 0; ni < 4; ni++)
#pragma unroll
            for (int r2 = 0; r2 < 4; r2++) {
                int m = bm0 + wm + mi * 16 + lh * 4 + r2;
                if (m < M) {
                    int nc = bn0 + wn + ni * 16 + lr;
                    float v = acc[mi][ni][r2];
                    if (OUTF) ((float*)Cv)[(size_t)m * N + nc] = v + bias[nc];
                    else      ((u16*)Cv)[(size_t)m * N + nc] = f2bf(v);
                }
            }
}

// ============ attention ============
// pglob layout: row rid = (bi*8+hd)*5+q, col s = j*5 + t5.

// --- fused: av scores (-> pglob) + va attention (-> cat V-rows) ---
// grid 1280 = chunk(5) x bh(256); 256 thr; thread owns key/query s = chunk*256+t
__global__ __launch_bounds__(256) void av_scores_va(const u16* __restrict__ vqkv,
                                                    const u16* __restrict__ aqkv,
                                                    const float* __restrict__ mask,
                                                    float* __restrict__ pglob,
                                                    u16* __restrict__ cat) {
    __shared__ float qa[5][64], ka[5][64], vaS[5][64];
    const int blk = blockIdx.x;
    const int chunk = blk % 5;
    const int bh = blk / 5;
    const int bi = bh >> 3, hd = bh & 7;
    const int t = threadIdx.x;
    for (int i = t; i < 320; i += 256) {
        int tt = i >> 6, d = i & 63;
        const size_t ab = (size_t)(bi * 5 + tt) * 1536 + hd * 64 + d;
        qa[tt][d]  = bf2f(aqkv[ab]);
        ka[tt][d]  = bf2f(aqkv[ab + 512]);
        vaS[tt][d] = bf2f(aqkv[ab + 1024]);
    }
    __syncthreads();
    const int s = chunk * 256 + t;          // 0..1279
    const int j = s / 5, t5 = s - j * 5;
    const int row = (bi * 5 + t5) * 256 + j;
    const u16* xrow = &vqkv[(size_t)row * 1536 + hd * 64];

    // ---- av scores: kv_row . qa_q -> pglob ----
    {
        float a0 = 0, a1 = 0, a2 = 0, a3 = 0, a4 = 0;
#pragma unroll
        for (int d = 0; d < 64; d += 8) {
            u16x8 v8 = *(const u16x8*)&xrow[512 + d];
#pragma unroll
            for (int jj = 0; jj < 8; jj++) {
                float f = bf2f(v8[jj]);
                a0 += f * qa[0][d + jj];
                a1 += f * qa[1][d + jj];
                a2 += f * qa[2][d + jj];
                a3 += f * qa[3][d + jj];
                a4 += f * qa[4][d + jj];
            }
        }
        const size_t base = (size_t)bh * 5 * 1280 + s;
        pglob[base]        = a0 * 0.125f;
        pglob[base + 1280] = a1 * 0.125f;
        pglob[base + 2560] = a2 * 0.125f;
        pglob[base + 3840] = a3 * 0.125f;
        pglob[base + 5120] = a4 * 0.125f;
    }

    // ---- va attention: qv_row vs ka, softmax5, @ va -> cat ----
    {
        float r0 = 0, r1 = 0, r2 = 0, r3 = 0, r4 = 0;
#pragma unroll
        for (int d = 0; d < 64; d += 8) {
            u16x8 q8 = *(const u16x8*)&xrow[d];
#pragma unroll
            for (int jj = 0; jj < 8; jj++) {
                float f = bf2f(q8[jj]);
                r0 += f * ka[0][d + jj];
                r1 += f * ka[1][d + jj];
                r2 += f * ka[2][d + jj];
                r3 += f * ka[3][d + jj];
                r4 += f * ka[4][d + jj];
            }
        }
        const float mval = mask[row] * 0.125f;
        r0 *= mval; r1 *= mval; r2 *= mval; r3 *= mval; r4 *= mval;
        float mx = fmaxf(fmaxf(fmaxf(r0, r1), fmaxf(r2, r3)), r4);
        float e0 = __expf(r0 - mx), e1 = __expf(r1 - mx), e2 = __expf(r2 - mx);
        float e3 = __expf(r3 - mx), e4 = __expf(r4 - mx);
        const float inv = 1.f / (e0 + e1 + e2 + e3 + e4);
        e0 *= inv; e1 *= inv; e2 *= inv; e3 *= inv; e4 *= inv;
        const size_t orow = ((size_t)row + (size_t)(bi * 5 + t5) + 1) * 512 + hd * 64;
        // row = (bi*5+t5)*256+j -> global token index (bi*5+t5)*257 + 1 + j
#pragma unroll
        for (int d = 0; d < 64; d += 8) {
            u16x8 o8;
#pragma unroll
            for (int jj = 0; jj < 8; jj++) {
                float o = e0 * vaS[0][d + jj] + e1 * vaS[1][d + jj] + e2 * vaS[2][d + jj] +
                          e3 * vaS[3][d + jj] + e4 * vaS[4][d + jj];
                o8[jj] = f2bf(o);
            }
            *(u16x8*)&cat[orow + d] = o8;
        }
    }
}

__global__ __launch_bounds__(256) void av_softmax(float* __restrict__ pglob) {
    const int wave = threadIdx.x >> 6, lane = threadIdx.x & 63;
    const int rid = blockIdx.x * 4 + wave;
    float* row = pglob + (size_t)rid * 1280;
    float v[20];
    float mx = -3.4e38f;
#pragma unroll
    for (int i = 0; i < 20; i++) {
        v[i] = row[lane + i * 64];
        mx = fmaxf(mx, v[i]);
    }
#pragma unroll
    for (int off = 32; off > 0; off >>= 1) mx = fmaxf(mx, __shfl_xor(mx, off));
    float sum = 0.f;
#pragma unroll
    for (int i = 0; i < 20; i++) {
        v[i] = __expf(v[i] - mx);
        sum += v[i];
    }
#pragma unroll
    for (int off = 32; off > 0; off >>= 1) sum += __shfl_xor(sum, off);
    const float inv = 1.f / sum;
#pragma unroll
    for (int i = 0; i < 20; i++) row[lane + i * 64] = v[i] * inv;
}

// --- PV partials. grid 2048 = (bh)(256) x jc(8); 320 thr, wave=q, lane=d ---
__global__ __launch_bounds__(320) void av_pv(const u16* __restrict__ vqkv,
                                             const float* __restrict__ pglob,
                                             float* __restrict__ avpart) {
    __shared__ float pl[5][160];
    const int blk = blockIdx.x;
    const int jc = blk & 7;
    const int bh = blk >> 3;
    const int bi = bh >> 3, hd = bh & 7;
    const int t = threadIdx.x;
    for (int ii = t; ii < 800; ii += 320) {
        int q = ii / 160, i = ii - q * 160;
        pl[q][i] = pglob[((size_t)bh * 5 + q) * 1280 + jc * 160 + i];
    }
    __syncthreads();
    const int wave = t >> 6, lane = t & 63;   // wave = q
    float acc = 0.f;
    const int j0 = jc * 32;
    for (int jj = 0; jj < 32; jj++) {
        const int j = j0 + jj;
#pragma unroll
        for (int t5 = 0; t5 < 5; t5++) {
            float v = bf2f(vqkv[(size_t)((bi * 5 + t5) * 256 + j) * 1536 + 1024 + hd * 64 + lane]);
            acc += pl[wave][jj * 5 + t5] * v;
        }
    }
    avpart[((size_t)jc * 1280 + (size_t)bh * 5 + wave) * 64 + lane] = acc;
}

__global__ __launch_bounds__(256) void av_write(const float* __restrict__ avpart,
                                                u16* __restrict__ cat) {
    const int idx = blockIdx.x * 256 + threadIdx.x;
    const int d = idx & 63;
    const int r = idx >> 6;
    const int q = r % 5, bh = r / 5;
    const int bi = bh >> 3, hd = bh & 7;
    float s = 0.f;
#pragma unroll
    for (int jc = 0; jc < 8; jc++) s += avpart[((size_t)jc * 1280 + r) * 64 + d];
    cat[(size_t)((bi * 5 + q) * 257) * 512 + hd * 64 + d] = f2bf(s);
}

extern "C" void kernel_launch(void* const* d_in, const int* in_sizes, int n_in,
                              void* d_out, int out_size, void* d_ws, size_t ws_size,
                              hipStream_t stream) {
    const float* x    = (const float*)d_in[0];  // (160,257,512) f32
    const float* mask = (const float*)d_in[1];  // (160,256) f32
    const float* Wv   = (const float*)d_in[2];  // (512,1536) f32
    const float* Wa   = (const float*)d_in[3];  // (512,1536) f32
    const float* Wo   = (const float*)d_in[4];  // (512,512) f32
    const float* bo   = (const float*)d_in[5];  // (512,) f32
    float* out = (float*)d_out;

    char* ws = (char*)d_ws;
    u16* xb   = (u16*)(ws);                   // 42,106,880 B
    u16* WvT  = (u16*)(ws + 42106880);        //  1,572,864 B
    u16* WaT  = (u16*)(ws + 43679744);        //  1,572,864 B
    u16* WoT  = (u16*)(ws + 45252608);        //    524,288 B
    u16* aqkv = (u16*)(ws + 45776896);        //    491,520 B
    u16* vqkv = (u16*)(ws + 46268416);        // 125,829,120 B
    u16* cat  = (u16*)(ws + 172097536);       // 42,106,880 B  -> ~214.2 MB
    // xb is dead after the projection GEMMs; reuse as av scratch:
    float* pglob  = (float*)(ws);             // 6,553,600 B
    float* avpart = (float*)(ws + 6553600);   // 2,621,440 B

    prep<<<dim3(10728), 256, 0, stream>>>(x, Wv, Wa, Wo, xb, WvT, WaT, WoT);

    // a_qkv = A @ Wa_qkv
    gemm_k<2, 0><<<dim3(12, 2), 256, 0, stream>>>(xb, WaT, aqkv, nullptr, 160, 1536, 512);

    // v_qkv = V @ Wv_qkv  (pipelined 256^2 + XCD swizzle; M=40960 exact)
    gemm_big<1, 0><<<dim3(6, 160), 1024, 0, stream>>>(xb, WvT, vqkv, nullptr, 40960, 1536);

    // av scores + va attention (fused; xb dead now -> pglob may overwrite it)
    av_scores_va<<<dim3(1280), 256, 0, stream>>>(vqkv, aqkv, mask, pglob, cat);
    av_softmax<<<dim3(320), 256, 0, stream>>>(pglob);
    av_pv<<<dim3(2048), 320, 0, stream>>>(vqkv, pglob, avpart);
    av_write<<<dim3(320), 256, 0, stream>>>(avpart, cat);

    // out = cat @ Wo + bo  (M=41120 -> 161 m-blocks, clamped)
    gemm_big<0, 1><<<dim3(2, 161), 1024, 0, stream>>>(cat, WoT, out, bo, 41120, 512);
}

// Round 13
// 228.887 us; speedup vs baseline: 1.6127x; 1.1103x over previous
//
#include <hip/hip_runtime.h>
#include <hip/hip_bf16.h>

typedef unsigned short u16;
typedef __bf16 bf16x8 __attribute__((ext_vector_type(8)));
typedef u16 u16x8 __attribute__((ext_vector_type(8)));
typedef float f32x4 __attribute__((ext_vector_type(4)));

__device__ __forceinline__ float bf2f(u16 u) {
    return __uint_as_float(((unsigned)u) << 16);
}
__device__ __forceinline__ u16 f2bf(float f) {
    unsigned u = __float_as_uint(f);
    unsigned r = (u + 0x7fffu + ((u >> 16) & 1u)) >> 16;
    return (u16)r;
}

// async global->LDS, 16B per lane. dst is wave-uniform base; HW adds lane*16.
__device__ __forceinline__ void gl_lds16(const u16* g, u16* l) {
    __builtin_amdgcn_global_load_lds(
        (const __attribute__((address_space(1))) void*)g,
        (__attribute__((address_space(3))) void*)l, 16, 0, 0);
}

// ---------------- fused prep: x f32->bf16 convert + 3 weight transposes ----------------
__global__ __launch_bounds__(256) void prep(const float* __restrict__ x,
                                            const float* __restrict__ Wv,
                                            const float* __restrict__ Wa,
                                            const float* __restrict__ Wo,
                                            u16* __restrict__ xb,
                                            u16* __restrict__ WvT,
                                            u16* __restrict__ WaT,
                                            u16* __restrict__ WoT) {
    __shared__ float tile[64][65];
    int blk = blockIdx.x;
    if (blk < 10280) {
        int i = (blk * 256 + threadIdx.x) * 8;
        float4 a = *(const float4*)&x[i];
        float4 b = *(const float4*)&x[i + 4];
        u16x8 o;
        o[0] = f2bf(a.x); o[1] = f2bf(a.y); o[2] = f2bf(a.z); o[3] = f2bf(a.w);
        o[4] = f2bf(b.x); o[5] = f2bf(b.y); o[6] = f2bf(b.z); o[7] = f2bf(b.w);
        *(u16x8*)&xb[i] = o;
        return;
    }
    blk -= 10280;
    const float* W; u16* WT; int N;
    if (blk < 192)      { W = Wv; WT = WvT; N = 1536; }
    else if (blk < 384) { W = Wa; WT = WaT; N = 1536; blk -= 192; }
    else                { W = Wo; WT = WoT; N = 512;  blk -= 384; }
    const int K = 512;
    const int nt = N >> 6;
    const int k0 = (blk / nt) << 6;
    const int n0 = (blk % nt) << 6;
    for (int i = threadIdx.x; i < 4096; i += 256) {
        int r = i >> 6, c = i & 63;
        tile[r][c] = W[(size_t)(k0 + r) * N + n0 + c];
    }
    __syncthreads();
    for (int i = threadIdx.x; i < 4096; i += 256) {
        int r = i >> 6, c = i & 63;
        WT[(size_t)(n0 + r) * K + k0 + c] = f2bf(tile[c][r]);
    }
}

// ---------------- pipelined 256x256 GEMM template (out-proj), K=512 ----------------
// round-11/12 verified: counted vmcnt, both-sides swizzle (0 conflicts), XCD swizzle.
template <int MODE, int OUTF>
__global__ __launch_bounds__(1024) void gemm_big(const u16* __restrict__ A,
                                                 const u16* __restrict__ Bt,
                                                 void* __restrict__ Cv,
                                                 const float* __restrict__ bias,
                                                 int M, int N) {
    __shared__ u16 As[2][256][64];
    __shared__ u16 Bs[2][256][64];
    const int t = threadIdx.x;
    const int nwg = gridDim.x * gridDim.y;
    const int orig = blockIdx.y * gridDim.x + blockIdx.x;
    const int qc = nwg >> 3, rc = nwg & 7;
    const int xcd = orig & 7, slot = orig >> 3;
    const int wgid = (xcd < rc ? xcd * (qc + 1) : rc * (qc + 1) + (xcd - rc) * qc) + slot;
    const int bn0 = (wgid % gridDim.x) * 256;
    const int bm0 = (wgid / gridDim.x) * 256;
    const int wave = t >> 6, lane = t & 63;
    const int wm = (wave >> 2) * 64, wn = (wave & 3) * 64;
    const int lr = lane & 15, lh = lane >> 4;
    const int xr = (lr & 7) << 3;
    u16* AsF = &As[0][0][0];
    u16* BsF = &Bs[0][0][0];

    const int gsa = ((lane & 7) ^ (lane >> 3)) * 8;
    auto stage = [&](int buf, int kt_) {
        const int kc = kt_ * 64;
#pragma unroll
        for (int j = 0; j < 2; j++) {
            int c0 = j * 1024 + wave * 64;
            int row = (c0 + lane) >> 3;
            int r = bm0 + row;
            long ga;
            if (MODE == 0) ga = (r < M) ? (long)r : 0l;
            else           ga = (long)(r >> 8) * 257 + (r & 255) + 1;
            gl_lds16(&A[ga * 512 + kc + gsa], AsF + buf * 16384 + c0 * 8);
            gl_lds16(&Bt[(long)(bn0 + row) * 512 + kc + gsa], BsF + buf * 16384 + c0 * 8);
        }
    };

    f32x4 acc[4][4] = {};

    stage(0, 0);
    __builtin_amdgcn_sched_barrier(0);
    stage(1, 1);
    __builtin_amdgcn_sched_barrier(0);
    asm volatile("s_waitcnt vmcnt(0)" ::: "memory");
    __builtin_amdgcn_s_barrier();
    __builtin_amdgcn_sched_barrier(0);

    int cur = 0;
    for (int kt = 0; kt < 8; kt++) {
        __builtin_amdgcn_s_setprio(1);
#pragma unroll
        for (int kk = 0; kk < 2; kk++) {
            bf16x8 af[4], bfr[4];
#pragma unroll
            for (int mi = 0; mi < 4; mi++)
                af[mi] = *(const bf16x8*)&As[cur][wm + mi * 16 + lr][(kk * 32 + lh * 8) ^ xr];
#pragma unroll
            for (int ni = 0; ni < 4; ni++)
                bfr[ni] = *(const bf16x8*)&Bs[cur][wn + ni * 16 + lr][(kk * 32 + lh * 8) ^ xr];
#pragma unroll
            for (int mi = 0; mi < 4; mi++)
#pragma unroll
                for (int ni = 0; ni < 4; ni++)
                    acc[mi][ni] = __builtin_amdgcn_mfma_f32_16x16x32_bf16(
                        af[mi], bfr[ni], acc[mi][ni], 0, 0, 0);
        }
        __builtin_amdgcn_s_setprio(0);
        if (kt == 7) break;
        __builtin_amdgcn_sched_barrier(0);
        __builtin_amdgcn_s_barrier();
        __builtin_amdgcn_sched_barrier(0);
        if (kt + 2 < 8) {
            stage(cur, kt + 2);
            __builtin_amdgcn_sched_barrier(0);
            asm volatile("s_waitcnt vmcnt(4)" ::: "memory");
        } else {
            asm volatile("s_waitcnt vmcnt(0)" ::: "memory");
        }
        __builtin_amdgcn_sched_barrier(0);
        __builtin_amdgcn_s_barrier();
        __builtin_amdgcn_sched_barrier(0);
        cur ^= 1;
    }

#pragma unroll
    for (int mi = 0; mi < 4; mi++)
#pragma unroll
        for (int ni = 0; ni < 4; ni++)
#pragma unroll
            for (int r2 = 0; r2 < 4; r2++) {
                int m = bm0 + wm + mi * 16 + lh * 4 + r2;
                if (m < M) {
                    int nc = bn0 + wn + ni * 16 + lr;
                    float v = acc[mi][ni][r2];
                    if (OUTF) ((float*)Cv)[(size_t)m * N + nc] = v + bias[nc];
                    else      ((u16*)Cv)[(size_t)m * N + nc] = f2bf(v);
                }
            }
}

// ---------------- merged V-QKV + A-QKV GEMM ----------------
// grid 966 (1-D): wgid<960 -> V-proj tile (bn 6 x bm 160); wgid>=960 -> A-proj
// tile (bm0=0, rows r*257 clamp r<160, out aqkv). Same pipeline as gemm_big.
__global__ __launch_bounds__(1024) void gemm_bigv(const u16* __restrict__ A,
                                                  const u16* __restrict__ BtV,
                                                  const u16* __restrict__ BtA,
                                                  u16* __restrict__ Cv,
                                                  u16* __restrict__ Ca) {
    __shared__ u16 As[2][256][64];
    __shared__ u16 Bs[2][256][64];
    const int t = threadIdx.x;
    const int nwg = gridDim.x;                 // 966
    const int orig = blockIdx.x;
    const int qc = nwg >> 3, rc = nwg & 7;
    const int xcd = orig & 7, slot = orig >> 3;
    const int wgid = (xcd < rc ? xcd * (qc + 1) : rc * (qc + 1) + (xcd - rc) * qc) + slot;
    const bool am = (wgid >= 960);             // A-proj section (uniform per block)
    const int bn0 = am ? (wgid - 960) * 256 : (wgid % 6) * 256;
    const int bm0 = am ? 0 : (wgid / 6) * 256;
    const u16* Bt = am ? BtA : BtV;
    const int wave = t >> 6, lane = t & 63;
    const int wm = (wave >> 2) * 64, wn = (wave & 3) * 64;
    const int lr = lane & 15, lh = lane >> 4;
    const int xr = (lr & 7) << 3;
    u16* AsF = &As[0][0][0];
    u16* BsF = &Bs[0][0][0];

    const int gsa = ((lane & 7) ^ (lane >> 3)) * 8;
    auto stage = [&](int buf, int kt_) {
        const int kc = kt_ * 64;
#pragma unroll
        for (int j = 0; j < 2; j++) {
            int c0 = j * 1024 + wave * 64;
            int row = (c0 + lane) >> 3;
            long ga;
            if (am) { int rr = (row < 160) ? row : 0; ga = (long)rr * 257; }
            else    { int r = bm0 + row;  ga = (long)(r >> 8) * 257 + (r & 255) + 1; }
            gl_lds16(&A[ga * 512 + kc + gsa], AsF + buf * 16384 + c0 * 8);
            gl_lds16(&Bt[(long)(bn0 + row) * 512 + kc + gsa], BsF + buf * 16384 + c0 * 8);
        }
    };

    f32x4 acc[4][4] = {};

    stage(0, 0);
    __builtin_amdgcn_sched_barrier(0);
    stage(1, 1);
    __builtin_amdgcn_sched_barrier(0);
    asm volatile("s_waitcnt vmcnt(0)" ::: "memory");
    __builtin_amdgcn_s_barrier();
    __builtin_amdgcn_sched_barrier(0);

    int cur = 0;
    for (int kt = 0; kt < 8; kt++) {
        __builtin_amdgcn_s_setprio(1);
#pragma unroll
        for (int kk = 0; kk < 2; kk++) {
            bf16x8 af[4], bfr[4];
#pragma unroll
            for (int mi = 0; mi < 4; mi++)
                af[mi] = *(const bf16x8*)&As[cur][wm + mi * 16 + lr][(kk * 32 + lh * 8) ^ xr];
#pragma unroll
            for (int ni = 0; ni < 4; ni++)
                bfr[ni] = *(const bf16x8*)&Bs[cur][wn + ni * 16 + lr][(kk * 32 + lh * 8) ^ xr];
#pragma unroll
            for (int mi = 0; mi < 4; mi++)
#pragma unroll
                for (int ni = 0; ni < 4; ni++)
                    acc[mi][ni] = __builtin_amdgcn_mfma_f32_16x16x32_bf16(
                        af[mi], bfr[ni], acc[mi][ni], 0, 0, 0);
        }
        __builtin_amdgcn_s_setprio(0);
        if (kt == 7) break;
        __builtin_amdgcn_sched_barrier(0);
        __builtin_amdgcn_s_barrier();
        __builtin_amdgcn_sched_barrier(0);
        if (kt + 2 < 8) {
            stage(cur, kt + 2);
            __builtin_amdgcn_sched_barrier(0);
            asm volatile("s_waitcnt vmcnt(4)" ::: "memory");
        } else {
            asm volatile("s_waitcnt vmcnt(0)" ::: "memory");
        }
        __builtin_amdgcn_sched_barrier(0);
        __builtin_amdgcn_s_barrier();
        __builtin_amdgcn_sched_barrier(0);
        cur ^= 1;
    }

#pragma unroll
    for (int mi = 0; mi < 4; mi++)
#pragma unroll
        for (int ni = 0; ni < 4; ni++)
#pragma unroll
            for (int r2 = 0; r2 < 4; r2++) {
                int m = bm0 + wm + mi * 16 + lh * 4 + r2;
                int nc = bn0 + wn + ni * 16 + lr;
                float v = acc[mi][ni][r2];
                if (am) {
                    if (m < 160) Ca[(size_t)m * 1536 + nc] = f2bf(v);
                } else {
                    Cv[(size_t)m * 1536 + nc] = f2bf(v);
                }
            }
}

// ============ attention ============
// pglob holds RAW scaled scores; softmax happens in av_finish (in LDS).
// pglob layout: row rid = (bi*8+hd)*5+q, col s = j*5 + t5.

// --- fused: av scores (-> pglob) + va attention (-> cat V-rows) ---
__global__ __launch_bounds__(256) void av_scores_va(const u16* __restrict__ vqkv,
                                                    const u16* __restrict__ aqkv,
                                                    const float* __restrict__ mask,
                                                    float* __restrict__ pglob,
                                                    u16* __restrict__ cat) {
    __shared__ float qa[5][64], ka[5][64], vaS[5][64];
    const int blk = blockIdx.x;
    const int chunk = blk % 5;
    const int bh = blk / 5;
    const int bi = bh >> 3, hd = bh & 7;
    const int t = threadIdx.x;
    for (int i = t; i < 320; i += 256) {
        int tt = i >> 6, d = i & 63;
        const size_t ab = (size_t)(bi * 5 + tt) * 1536 + hd * 64 + d;
        qa[tt][d]  = bf2f(aqkv[ab]);
        ka[tt][d]  = bf2f(aqkv[ab + 512]);
        vaS[tt][d] = bf2f(aqkv[ab + 1024]);
    }
    __syncthreads();
    const int s = chunk * 256 + t;          // 0..1279
    const int j = s / 5, t5 = s - j * 5;
    const int row = (bi * 5 + t5) * 256 + j;
    const u16* xrow = &vqkv[(size_t)row * 1536 + hd * 64];

    // ---- av scores: kv_row . qa_q -> pglob (raw, scaled) ----
    {
        float a0 = 0, a1 = 0, a2 = 0, a3 = 0, a4 = 0;
#pragma unroll
        for (int d = 0; d < 64; d += 8) {
            u16x8 v8 = *(const u16x8*)&xrow[512 + d];
#pragma unroll
            for (int jj = 0; jj < 8; jj++) {
                float f = bf2f(v8[jj]);
                a0 += f * qa[0][d + jj];
                a1 += f * qa[1][d + jj];
                a2 += f * qa[2][d + jj];
                a3 += f * qa[3][d + jj];
                a4 += f * qa[4][d + jj];
            }
        }
        const size_t base = (size_t)bh * 5 * 1280 + s;
        pglob[base]        = a0 * 0.125f;
        pglob[base + 1280] = a1 * 0.125f;
        pglob[base + 2560] = a2 * 0.125f;
        pglob[base + 3840] = a3 * 0.125f;
        pglob[base + 5120] = a4 * 0.125f;
    }

    // ---- va attention: qv_row vs ka, softmax5, @ va -> cat V-row ----
    {
        float r0 = 0, r1 = 0, r2 = 0, r3 = 0, r4 = 0;
#pragma unroll
        for (int d = 0; d < 64; d += 8) {
            u16x8 q8 = *(const u16x8*)&xrow[d];
#pragma unroll
            for (int jj = 0; jj < 8; jj++) {
                float f = bf2f(q8[jj]);
                r0 += f * ka[0][d + jj];
                r1 += f * ka[1][d + jj];
                r2 += f * ka[2][d + jj];
                r3 += f * ka[3][d + jj];
                r4 += f * ka[4][d + jj];
            }
        }
        const float mval = mask[row] * 0.125f;
        r0 *= mval; r1 *= mval; r2 *= mval; r3 *= mval; r4 *= mval;
        float mx = fmaxf(fmaxf(fmaxf(r0, r1), fmaxf(r2, r3)), r4);
        float e0 = __expf(r0 - mx), e1 = __expf(r1 - mx), e2 = __expf(r2 - mx);
        float e3 = __expf(r3 - mx), e4 = __expf(r4 - mx);
        const float inv = 1.f / (e0 + e1 + e2 + e3 + e4);
        e0 *= inv; e1 *= inv; e2 *= inv; e3 *= inv; e4 *= inv;
        const size_t orow = ((size_t)row + (size_t)(bi * 5 + t5) + 1) * 512 + hd * 64;
#pragma unroll
        for (int d = 0; d < 64; d += 8) {
            u16x8 o8;
#pragma unroll
            for (int jj = 0; jj < 8; jj++) {
                float o = e0 * vaS[0][d + jj] + e1 * vaS[1][d + jj] + e2 * vaS[2][d + jj] +
                          e3 * vaS[3][d + jj] + e4 * vaS[4][d + jj];
                o8[jj] = f2bf(o);
            }
            *(u16x8*)&cat[orow + d] = o8;
        }
    }
}

// --- fused av finish: softmax (in LDS) + PV + reduce + cat write ---
// grid 256 = (bi,hd); 512 threads = 8 waves. pl = 25.6KB, pbuf = 10KB.
__global__ __launch_bounds__(512) void av_finish(const u16* __restrict__ vqkv,
                                                 const float* __restrict__ pglob,
                                                 u16* __restrict__ cat) {
    __shared__ float pl[5][1280];
    __shared__ float pbuf[8][5][64];
    const int bh = blockIdx.x;
    const int bi = bh >> 3, hd = bh & 7;
    const int t = threadIdx.x;
    for (int i = t; i < 6400; i += 512) {
        pl[0][i] = pglob[(size_t)bh * 6400 + i];   // pl is contiguous [5][1280]
    }
    __syncthreads();
    const int wave = t >> 6, lane = t & 63;
    if (wave < 5) {
        float v[20];
        float mx = -3.4e38f;
#pragma unroll
        for (int i = 0; i < 20; i++) {
            v[i] = pl[wave][lane + i * 64];
            mx = fmaxf(mx, v[i]);
        }
#pragma unroll
        for (int off = 32; off > 0; off >>= 1) mx = fmaxf(mx, __shfl_xor(mx, off));
        float sum = 0.f;
#pragma unroll
        for (int i = 0; i < 20; i++) {
            v[i] = __expf(v[i] - mx);
            sum += v[i];
        }
#pragma unroll
        for (int off = 32; off > 0; off >>= 1) sum += __shfl_xor(sum, off);
        const float inv = 1.f / sum;
#pragma unroll
        for (int i = 0; i < 20; i++) pl[wave][lane + i * 64] = v[i] * inv;
    }
    __syncthreads();
    // PV: wave owns j in [wave*32, wave*32+32); lane = d
    {
        float a0 = 0, a1 = 0, a2 = 0, a3 = 0, a4 = 0;
        const int j0 = wave * 32;
        for (int jj = 0; jj < 32; jj++) {
            const int j = j0 + jj;
#pragma unroll
            for (int t5 = 0; t5 < 5; t5++) {
                float v = bf2f(vqkv[(size_t)((bi * 5 + t5) * 256 + j) * 1536 + 1024 + hd * 64 + lane]);
                const int s = j * 5 + t5;
                a0 += pl[0][s] * v;
                a1 += pl[1][s] * v;
                a2 += pl[2][s] * v;
                a3 += pl[3][s] * v;
                a4 += pl[4][s] * v;
            }
        }
        pbuf[wave][0][lane] = a0;
        pbuf[wave][1][lane] = a1;
        pbuf[wave][2][lane] = a2;
        pbuf[wave][3][lane] = a3;
        pbuf[wave][4][lane] = a4;
    }
    __syncthreads();
    if (t < 320) {
        const int q = t >> 6, d = t & 63;
        float s = 0.f;
#pragma unroll
        for (int w = 0; w < 8; w++) s += pbuf[w][q][d];
        cat[(size_t)((bi * 5 + q) * 257) * 512 + hd * 64 + d] = f2bf(s);
    }
}

extern "C" void kernel_launch(void* const* d_in, const int* in_sizes, int n_in,
                              void* d_out, int out_size, void* d_ws, size_t ws_size,
                              hipStream_t stream) {
    const float* x    = (const float*)d_in[0];  // (160,257,512) f32
    const float* mask = (const float*)d_in[1];  // (160,256) f32
    const float* Wv   = (const float*)d_in[2];  // (512,1536) f32
    const float* Wa   = (const float*)d_in[3];  // (512,1536) f32
    const float* Wo   = (const float*)d_in[4];  // (512,512) f32
    const float* bo   = (const float*)d_in[5];  // (512,) f32
    float* out = (float*)d_out;

    char* ws = (char*)d_ws;
    u16* xb   = (u16*)(ws);                   // 42,106,880 B
    u16* WvT  = (u16*)(ws + 42106880);        //  1,572,864 B
    u16* WaT  = (u16*)(ws + 43679744);        //  1,572,864 B
    u16* WoT  = (u16*)(ws + 45252608);        //    524,288 B
    u16* aqkv = (u16*)(ws + 45776896);        //    491,520 B
    u16* vqkv = (u16*)(ws + 46268416);        // 125,829,120 B
    u16* cat  = (u16*)(ws + 172097536);       // 42,106,880 B  -> ~214.2 MB
    // xb dead after gemm_bigv; reuse as av scratch:
    float* pglob = (float*)(ws);              // 6,553,600 B

    prep<<<dim3(10728), 256, 0, stream>>>(x, Wv, Wa, Wo, xb, WvT, WaT, WoT);

    // v_qkv (960 tiles) + a_qkv (6 tiles) in one pipelined launch
    gemm_bigv<<<dim3(966), 1024, 0, stream>>>(xb, WvT, WaT, vqkv, aqkv);

    // av raw scores + va attention (xb dead now -> pglob may overwrite it)
    av_scores_va<<<dim3(1280), 256, 0, stream>>>(vqkv, aqkv, mask, pglob, cat);

    // softmax + PV + reduce + cat A-row write, all in one kernel
    av_finish<<<dim3(256), 512, 0, stream>>>(vqkv, pglob, cat);

    // out = cat @ Wo + bo  (M=41120 -> 161 m-blocks, clamped)
    gemm_big<0, 1><<<dim3(2, 161), 1024, 0, stream>>>(cat, WoT, out, bo, 41120, 512);
}